// Round 14
// baseline (137.727 us; speedup 1.0000x reference)
//
#include <hip/hip_runtime.h>

// CTC batch cost (Keras: blank=C-1, full lengths). SINGLE fused kernel.
// One block/row: wave 1 = producer (gathers DIRECTLY from y_hat via
// global_load_lds's per-lane global source), wave 0 = consumer (VMEM-free
// loop, LDS reads only). R13 fit: per-chunk overhead h ~= 1400 cyc dominates
// (64 chunks = 37us of 71). R14: TC=128, NBUF=2 -> 8 chunks (amortize h 8x),
// and the counting-free producer pattern: issue stage(c+1) -> vmcnt(0) ->
// raw s_barrier. The wait hides under the consumer's ~10K-cyc chunk.
// LDS: sbuf 128KB + sblk 4KB = 132KB.
// DPP wave_shr:1 cross-lane shift; per-lane pow2 rescale every 4 steps
// ((p_min~2e-6)^4 = 2^-76 window decay -- safe; every-8 would underflow).

constexpr int   B_DIM = 64;
constexpr int   T_LEN = 1024;
constexpr int   C_DIM = 512;
constexpr int   L_LEN = 128;
constexpr int   BLANK = C_DIM - 1;
constexpr int   TC    = 128;           // timesteps per chunk
constexpr int   NCH   = T_LEN / TC;    // 8 chunks
constexpr float EPSF  = 1e-7f;
constexpr float LN2F  = 0.69314718055994530942f;

// lane l <- lane l-1, lane 0 <- 0 (DPP wave_shr:1, bound_ctrl=0-fill). VALU-only.
__device__ __forceinline__ float wshr1_f(float x) {
    return __int_as_float(__builtin_amdgcn_update_dpp(
        0, __float_as_int(x), 0x138, 0xf, 0xf, true));
}
__device__ __forceinline__ int wshr1_i(int x) {
    return __builtin_amdgcn_update_dpp(0, x, 0x138, 0xf, 0xf, true);
}

__global__ __launch_bounds__(128, 1)
void ctc_fused(const int* __restrict__ yt, const float* __restrict__ yh,
               float* __restrict__ out)
{
    __shared__ float sbuf[2][TC][2][64];      // [buf][i][0]=p(l0) [1]=p(l1), 128KB
    __shared__ float sblk[T_LEN / 64][64];    // blank[t>>6][t&63], 4KB

    const int b    = blockIdx.x;
    const int tid  = threadIdx.x;
    const int lane = tid & 63;
    const int wid  = tid >> 6;                // 0 = consumer, 1 = producer

    const int* __restrict__ lb = yt + b * L_LEN;
    const float* __restrict__ yhb = yh + (size_t)b * T_LEN * C_DIM;

    if (wid == 1) {
        // ---------------- producer: gather-staging directly from y_hat -----
        const int c1 = lb[2 * lane];                  // column for state 4l+1
        const int c3 = lb[2 * lane + 1];              // column for state 4l+3
        const float* g1 = yhb + c1;                   // per-lane source ptrs
        const float* g3 = yhb + c3;
        const float* gB = yhb + (size_t)lane * C_DIM + BLANK;  // lane<->timestep

        auto stage = [&](int ch) {                    // 2*TC size-4 gather loads
            float* d = &sbuf[ch & 1][0][0][0];
            const size_t t0 = (size_t)ch * TC;
#pragma unroll
            for (int i = 0; i < TC; ++i) {
                __builtin_amdgcn_global_load_lds(
                    (const __attribute__((address_space(1))) void*)(g1 + (t0 + i) * C_DIM),
                    (__attribute__((address_space(3))) void*)(d + i * 128), 4, 0, 0);
                __builtin_amdgcn_global_load_lds(
                    (const __attribute__((address_space(1))) void*)(g3 + (t0 + i) * C_DIM),
                    (__attribute__((address_space(3))) void*)(d + i * 128 + 64), 4, 0, 0);
            }
        };

        // blanks for ALL timesteps: 16 loads, lane l covers t = j*64+l
#pragma unroll
        for (int j = 0; j < T_LEN / 64; ++j) {
            __builtin_amdgcn_global_load_lds(
                (const __attribute__((address_space(1))) void*)(gB + (size_t)j * 64 * C_DIM),
                (__attribute__((address_space(3))) void*)&sblk[j][0], 4, 0, 0);
        }
        stage(0);
        asm volatile("s_waitcnt vmcnt(0)" ::: "memory");   // blanks + chunk 0 landed
        __builtin_amdgcn_sched_barrier(0);
        __builtin_amdgcn_s_barrier();                      // raw: no auto-drain
#pragma unroll 1
        for (int c = 0; c < NCH; ++c) {
            if (c + 1 < NCH) stage(c + 1);                 // lands while consumer does c
            asm volatile("s_waitcnt vmcnt(0)" ::: "memory");
            __builtin_amdgcn_sched_barrier(0);
            __builtin_amdgcn_s_barrier();
        }
    } else {
        // ---------------- consumer: LDS only in loop, zero VMEM ------------
        const int l0 = lb[2 * lane];
        const int l1 = lb[2 * lane + 1];
        const int lp = lane ? lb[2 * lane - 1] : 0;
        const float sk1 = (lane > 0 && l0 != lp && l0 != BLANK) ? 1.0f : 0.0f;
        const float sk3 = (l1 != l0 && l1 != BLANK) ? 1.0f : 0.0f;

        // "t=-1" init: a0=1 on lane 0 makes step t=0 produce exactly alpha0.
        float a0 = (lane == 0) ? 1.0f : 0.0f;
        float a1 = 0.0f, a2 = 0.0f, a3 = 0.0f, a4 = 0.0f;
        int   E  = 0;                                   // per-lane exponent
        float sSeed = (lane == 0) ? 0.0f : 1.0f;        // 2^(E_prev-E), 0 on lane 0

        __builtin_amdgcn_s_barrier();                   // matches producer prologue

        float r1[8], r3[8], rb[8];
#pragma unroll 1
        for (int c = 0; c < NCH; ++c) {
            __builtin_amdgcn_sched_barrier(0);          // no LDS reads above barrier
            const float* sb = &sbuf[c & 1][0][0][lane];
            const int t0 = c * TC;
#pragma unroll
            for (int i = 0; i < 8; ++i) {
                r1[i] = sb[i * 128];
                r3[i] = sb[i * 128 + 64];
                rb[i] = sblk[(t0 + i) >> 6][(t0 + i) & 63];
            }
#pragma unroll 1
            for (int tq = 0; tq < TC / 8; ++tq) {
#pragma unroll
                for (int i = 0; i < 8; ++i) {
                    const float P1 = r1[i] + EPSF;
                    const float P3 = r3[i] + EPSF;
                    const float Pb = rb[i] + EPSF;
                    if (tq < TC / 8 - 1) {
                        const int tn = tq * 8 + i + 8;
                        r1[i] = sb[tn * 128];
                        r3[i] = sb[tn * 128 + 64];
                        rb[i] = sblk[(t0 + tn) >> 6][(t0 + tn) & 63];
                    }

                    const float pa3 = wshr1_f(a3) * sSeed;  // alpha[4l-1]
                    const float n0 = Pb * (a0 + pa3);
                    const float n1 = P1 * (a1 + a0 + sk1 * pa3);
                    const float n2 = Pb * (a2 + a1);
                    const float n3 = P3 * (a3 + a2 + sk3 * a1);
                    const float n4 = Pb * (a4 + a3);
                    a0 = n0; a1 = n1; a2 = n2; a3 = n3; a4 = n4;

                    if ((i & 3) == 3) {
                        // per-lane rescale every 4 steps (decay >= ~2^-76)
                        const float m = fmaxf(fmaxf(fmaxf(a0, a1), fmaxf(a2, a3)), a4);
                        const bool has = m > 0.0f;
                        int eb = (int)((__float_as_uint(m) >> 23) & 0xFFu);
                        eb = eb < 1 ? 1 : eb;           // denormal m -> scale up
                        if (has) {
                            const float scl = __uint_as_float((unsigned)(254 - eb) << 23);
                            a0 *= scl; a1 *= scl; a2 *= scl; a3 *= scl; a4 *= scl;
                            E += eb - 127;
                        }
                        int pE = wshr1_i(E);
                        if (!has && lane > 0) E = pE;   // empty lane adopts E
                        pE = wshr1_i(E);
                        const int d = pE - E;
                        sSeed = (lane == 0 || d < -126)
                              ? 0.0f
                              : __uint_as_float((unsigned)(127 + (d > 126 ? 126 : d)) << 23);
                    }
                }
            }
            __builtin_amdgcn_sched_barrier(0);          // no LDS reads below barrier
            __builtin_amdgcn_s_barrier();
        }

        if (lane == 63)                                 // states 255 (a3) + 256 (a4)
            out[b] = -((log2f(a3 + a4) + (float)E) * LN2F);
    }
}

extern "C" void kernel_launch(void* const* d_in, const int* in_sizes, int n_in,
                              void* d_out, int out_size, void* d_ws, size_t ws_size,
                              hipStream_t stream)
{
    const int*   yt  = (const int*)d_in[0];
    const float* yh  = (const float*)d_in[1];
    float*       out = (float*)d_out;
    ctc_fused<<<dim3(B_DIM), dim3(128), 0, stream>>>(yt, yh, out);
}

// Round 15
// 69.956 us; speedup vs baseline: 1.9688x; 1.9688x over previous
//
#include <hip/hip_runtime.h>

// CTC batch cost (Keras: blank=C-1, full lengths). SINGLE fused kernel.
// One block/row, 3 waves: wave0 = consumer (VMEM-free DP loop, proven),
// waves 1+2 = producers, each gather-staging HALF of each chunk directly
// from y_hat via global_load_lds (per-lane global source, wave-uniform LDS
// dest). R14 lesson: scattered gathers cost ~160cyc each in the CU's
// address unit; one producer wave = 330K cyc. Two producer waves double
// issue parallelism; counted vmcnt(32) keeps 2 chunks in flight per wave
// (R13's winning pattern), raw s_barrier (no auto-drain) syncs the 3 waves.
// DPP wave_shr:1 cross-lane shift; per-lane pow2 rescale every 4 steps
// (unbounded dynamic range; absmax 0.0 since R2 whenever mechanics right).

constexpr int   B_DIM = 64;
constexpr int   T_LEN = 1024;
constexpr int   C_DIM = 512;
constexpr int   L_LEN = 128;
constexpr int   BLANK = C_DIM - 1;
constexpr int   TC    = 32;            // timesteps per chunk
constexpr int   NCH   = T_LEN / TC;    // 32 chunks
constexpr int   NBUF  = 4;             // chunk buffers in LDS
constexpr int   TH    = TC / 2;        // steps per producer wave
constexpr float EPSF  = 1e-7f;
constexpr float LN2F  = 0.69314718055994530942f;

// lane l <- lane l-1, lane 0 <- 0 (DPP wave_shr:1, bound_ctrl=0-fill). VALU-only.
__device__ __forceinline__ float wshr1_f(float x) {
    return __int_as_float(__builtin_amdgcn_update_dpp(
        0, __float_as_int(x), 0x138, 0xf, 0xf, true));
}
__device__ __forceinline__ int wshr1_i(int x) {
    return __builtin_amdgcn_update_dpp(0, x, 0x138, 0xf, 0xf, true);
}

__global__ __launch_bounds__(192, 1)
void ctc_fused(const int* __restrict__ yt, const float* __restrict__ yh,
               float* __restrict__ out)
{
    __shared__ float sbuf[NBUF][TC][2][64];   // [buf][i][0]=p(l0) [1]=p(l1), 64KB
    __shared__ float sblk[T_LEN / 64][64];    // blank[t>>6][t&63], 4KB

    const int b    = blockIdx.x;
    const int tid  = threadIdx.x;
    const int lane = tid & 63;
    const int wid  = tid >> 6;                // 0 consumer, 1-2 producers

    const int* __restrict__ lb = yt + b * L_LEN;
    const float* __restrict__ yhb = yh + (size_t)b * T_LEN * C_DIM;

    if (wid >= 1) {
        // -------- producers: gather-stage half a chunk each ----------------
        const int i0 = (wid == 1) ? 0 : TH;           // my half of the chunk
        const int c1 = lb[2 * lane];                  // column for state 4l+1
        const int c3 = lb[2 * lane + 1];              // column for state 4l+3
        const float* g1 = yhb + c1;                   // per-lane source ptrs
        const float* g3 = yhb + c3;
        const float* gB = yhb + (size_t)lane * C_DIM + BLANK;  // lane<->timestep

        auto stage_half = [&](int ch) {               // 2*TH = 32 size-4 loads
            float* d = &sbuf[ch & (NBUF - 1)][0][0][0];
            const size_t t0 = (size_t)ch * TC;
#pragma unroll
            for (int i = i0; i < i0 + TH; ++i) {
                __builtin_amdgcn_global_load_lds(
                    (const __attribute__((address_space(1))) void*)(g1 + (t0 + i) * C_DIM),
                    (__attribute__((address_space(3))) void*)(d + i * 128), 4, 0, 0);
                __builtin_amdgcn_global_load_lds(
                    (const __attribute__((address_space(1))) void*)(g3 + (t0 + i) * C_DIM),
                    (__attribute__((address_space(3))) void*)(d + i * 128 + 64), 4, 0, 0);
            }
        };

        if (wid == 2) {
            // blanks for ALL timesteps: 16 loads, lane l covers t = j*64+l
#pragma unroll
            for (int j = 0; j < T_LEN / 64; ++j) {
                __builtin_amdgcn_global_load_lds(
                    (const __attribute__((address_space(1))) void*)(gB + (size_t)j * 64 * C_DIM),
                    (__attribute__((address_space(3))) void*)&sblk[j][0], 4, 0, 0);
            }
        }
        asm volatile("s_waitcnt vmcnt(0)" ::: "memory");   // clean per-wave baseline
        stage_half(0);
        stage_half(1);                                     // 64 outstanding
        asm volatile("s_waitcnt vmcnt(32)" ::: "memory");  // my chunk-0 half landed
        __builtin_amdgcn_sched_barrier(0);
        __builtin_amdgcn_s_barrier();                      // raw: no auto-drain
#pragma unroll 1
        for (int c = 0; c < NCH; ++c) {
            if (c + 2 < NCH) {
                stage_half(c + 2);                         // 2 chunks in flight
                asm volatile("s_waitcnt vmcnt(32)" ::: "memory"); // c+1 half landed
            } else {
                asm volatile("s_waitcnt vmcnt(0)" ::: "memory");  // tail drain
            }
            __builtin_amdgcn_sched_barrier(0);
            __builtin_amdgcn_s_barrier();
        }
    } else {
        // -------- consumer: LDS only in loop, zero VMEM --------------------
        const int l0 = lb[2 * lane];
        const int l1 = lb[2 * lane + 1];
        const int lp = lane ? lb[2 * lane - 1] : 0;
        const float sk1 = (lane > 0 && l0 != lp && l0 != BLANK) ? 1.0f : 0.0f;
        const float sk3 = (l1 != l0 && l1 != BLANK) ? 1.0f : 0.0f;

        // "t=-1" init: a0=1 on lane 0 makes step t=0 produce exactly alpha0.
        float a0 = (lane == 0) ? 1.0f : 0.0f;
        float a1 = 0.0f, a2 = 0.0f, a3 = 0.0f, a4 = 0.0f;
        int   E  = 0;                                   // per-lane exponent
        float sSeed = (lane == 0) ? 0.0f : 1.0f;        // 2^(E_prev-E), 0 on lane 0

        __builtin_amdgcn_s_barrier();                   // matches producer prologue

        float r1[8], r3[8], rb[8];
#pragma unroll 1
        for (int c = 0; c < NCH; ++c) {
            __builtin_amdgcn_sched_barrier(0);          // no LDS reads above barrier
            const float* sb = &sbuf[c & (NBUF - 1)][0][0][lane];
            const int t0 = c * TC;
#pragma unroll
            for (int i = 0; i < 8; ++i) {
                r1[i] = sb[i * 128];
                r3[i] = sb[i * 128 + 64];
                rb[i] = sblk[(t0 + i) >> 6][(t0 + i) & 63];
            }
#pragma unroll
            for (int tq = 0; tq < TC / 8; ++tq) {
#pragma unroll
                for (int i = 0; i < 8; ++i) {
                    const float P1 = r1[i] + EPSF;
                    const float P3 = r3[i] + EPSF;
                    const float Pb = rb[i] + EPSF;
                    if (tq < TC / 8 - 1) {
                        const int tn = tq * 8 + i + 8;
                        r1[i] = sb[tn * 128];
                        r3[i] = sb[tn * 128 + 64];
                        rb[i] = sblk[(t0 + tn) >> 6][(t0 + tn) & 63];
                    }

                    const float pa3 = wshr1_f(a3) * sSeed;  // alpha[4l-1]
                    const float n0 = Pb * (a0 + pa3);
                    const float n1 = P1 * (a1 + a0 + sk1 * pa3);
                    const float n2 = Pb * (a2 + a1);
                    const float n3 = P3 * (a3 + a2 + sk3 * a1);
                    const float n4 = Pb * (a4 + a3);
                    a0 = n0; a1 = n1; a2 = n2; a3 = n3; a4 = n4;

                    if ((i & 3) == 3) {
                        // per-lane rescale every 4 steps (decay >= ~2^-93)
                        const float m = fmaxf(fmaxf(fmaxf(a0, a1), fmaxf(a2, a3)), a4);
                        const bool has = m > 0.0f;
                        int eb = (int)((__float_as_uint(m) >> 23) & 0xFFu);
                        eb = eb < 1 ? 1 : eb;           // denormal m -> scale up
                        if (has) {
                            const float scl = __uint_as_float((unsigned)(254 - eb) << 23);
                            a0 *= scl; a1 *= scl; a2 *= scl; a3 *= scl; a4 *= scl;
                            E += eb - 127;
                        }
                        int pE = wshr1_i(E);
                        if (!has && lane > 0) E = pE;   // empty lane adopts E
                        pE = wshr1_i(E);
                        const int d = pE - E;
                        sSeed = (lane == 0 || d < -126)
                              ? 0.0f
                              : __uint_as_float((unsigned)(127 + (d > 126 ? 126 : d)) << 23);
                    }
                }
            }
            __builtin_amdgcn_sched_barrier(0);          // no LDS reads below barrier
            __builtin_amdgcn_s_barrier();
        }

        if (lane == 63)                                 // states 255 (a3) + 256 (a4)
            out[b] = -((log2f(a3 + a4) + (float)E) * LN2F);
    }
}

extern "C" void kernel_launch(void* const* d_in, const int* in_sizes, int n_in,
                              void* d_out, int out_size, void* d_ws, size_t ws_size,
                              hipStream_t stream)
{
    const int*   yt  = (const int*)d_in[0];
    const float* yh  = (const float*)d_in[1];
    float*       out = (float*)d_out;
    ctc_fused<<<dim3(B_DIM), dim3(192), 0, stream>>>(yt, yh, out);
}

// Round 16
// 67.719 us; speedup vs baseline: 2.0338x; 1.0330x over previous
//
#include <hip/hip_runtime.h>

// CTC batch cost (Keras: blank=C-1, full lengths). SINGLE fused kernel.
// One block/row, 2 waves. R15 lesson: scattered gathers read ~the whole 2KB
// row through L1 anyway (128 random labels hit ~30/32 lines) while paying
// ~80cyc/load TA serialization. So: wave1 = producer STREAMS whole rows
// coalesced into LDS (2 x dwordx4 global_load_lds per t; issue ~5cyc);
// wave0 = consumer picks p[l0], p[l1] via LDS-gather ds_read_b32 (fixed
// per-lane offsets, ~4-way conflicts ok) and blank via uniform broadcast.
// Raw s_barrier sync (no auto-drain), drain-to-0 producer (hides under the
// consumer's ~2.5K-cyc chunk; R14's drain failure was scatter cost).
// DPP wave_shr:1 cross-lane shift; per-lane pow2 rescale every 4 steps
// (unbounded dynamic range; absmax 0.0 since R2 whenever mechanics right).

constexpr int   B_DIM = 64;
constexpr int   T_LEN = 1024;
constexpr int   C_DIM = 512;
constexpr int   L_LEN = 128;
constexpr int   BLANK = C_DIM - 1;
constexpr int   TC    = 32;            // timesteps per chunk
constexpr int   NCH   = T_LEN / TC;    // 32 chunks
constexpr float EPSF  = 1e-7f;
constexpr float LN2F  = 0.69314718055994530942f;

// lane l <- lane l-1, lane 0 <- 0 (DPP wave_shr:1, bound_ctrl=0-fill). VALU-only.
__device__ __forceinline__ float wshr1_f(float x) {
    return __int_as_float(__builtin_amdgcn_update_dpp(
        0, __float_as_int(x), 0x138, 0xf, 0xf, true));
}
__device__ __forceinline__ int wshr1_i(int x) {
    return __builtin_amdgcn_update_dpp(0, x, 0x138, 0xf, 0xf, true);
}

__global__ __launch_bounds__(128, 1)
void ctc_fused(const int* __restrict__ yt, const float* __restrict__ yh,
               float* __restrict__ out)
{
    __shared__ float sbuf[2][TC][C_DIM];      // whole rows, 2 x 64KB = 128KB

    const int b    = blockIdx.x;
    const int tid  = threadIdx.x;
    const int lane = tid & 63;
    const int wid  = tid >> 6;                // 0 = consumer, 1 = producer

    const int* __restrict__ lb = yt + b * L_LEN;
    const float* __restrict__ yhb = yh + (size_t)b * T_LEN * C_DIM;

    if (wid == 1) {
        // ---- producer: stream whole rows coalesced (no label reads) -------
        auto stage = [&](int ch) {            // TC rows x 2 dwordx4 loads
            float* d = &sbuf[ch & 1][0][0];
            const float* g = yhb + (size_t)ch * TC * C_DIM + lane * 4;
#pragma unroll
            for (int i = 0; i < TC; ++i) {
#pragma unroll
                for (int h = 0; h < 2; ++h) {
                    __builtin_amdgcn_global_load_lds(
                        (const __attribute__((address_space(1))) void*)
                            (g + i * C_DIM + h * 256),
                        (__attribute__((address_space(3))) void*)
                            (d + i * C_DIM + h * 256),
                        16, 0, 0);
                }
            }
        };

        stage(0);
        asm volatile("s_waitcnt vmcnt(0)" ::: "memory");
        __builtin_amdgcn_sched_barrier(0);
        __builtin_amdgcn_s_barrier();                      // raw: no auto-drain
#pragma unroll 1
        for (int c = 0; c < NCH; ++c) {
            if (c + 1 < NCH) stage(c + 1);                 // lands under consumer's chunk
            asm volatile("s_waitcnt vmcnt(0)" ::: "memory");
            __builtin_amdgcn_sched_barrier(0);
            __builtin_amdgcn_s_barrier();
        }
    } else {
        // ---- consumer: LDS-gather + DP chain, zero VMEM in loop -----------
        const int l0 = lb[2 * lane];
        const int l1 = lb[2 * lane + 1];
        const int lp = lane ? lb[2 * lane - 1] : 0;
        const float sk1 = (lane > 0 && l0 != lp && l0 != BLANK) ? 1.0f : 0.0f;
        const float sk3 = (l1 != l0 && l1 != BLANK) ? 1.0f : 0.0f;

        // "t=-1" init: a0=1 on lane 0 makes step t=0 produce exactly alpha0.
        float a0 = (lane == 0) ? 1.0f : 0.0f;
        float a1 = 0.0f, a2 = 0.0f, a3 = 0.0f, a4 = 0.0f;
        int   E  = 0;                                   // per-lane exponent
        float sSeed = (lane == 0) ? 0.0f : 1.0f;        // 2^(E_prev-E), 0 on lane 0

        __builtin_amdgcn_s_barrier();                   // matches producer prologue

        float r1[8], r3[8], rb[8];
#pragma unroll 1
        for (int c = 0; c < NCH; ++c) {
            __builtin_amdgcn_sched_barrier(0);          // no LDS reads above barrier
            const float* sb = &sbuf[c & 1][0][0];
#pragma unroll
            for (int i = 0; i < 8; ++i) {
                r1[i] = sb[i * C_DIM + l0];
                r3[i] = sb[i * C_DIM + l1];
                rb[i] = sb[i * C_DIM + BLANK];          // uniform -> broadcast
            }
#pragma unroll
            for (int tq = 0; tq < TC / 8; ++tq) {
#pragma unroll
                for (int i = 0; i < 8; ++i) {
                    const float P1 = r1[i] + EPSF;
                    const float P3 = r3[i] + EPSF;
                    const float Pb = rb[i] + EPSF;
                    if (tq < TC / 8 - 1) {
                        const int tn = tq * 8 + i + 8;
                        r1[i] = sb[tn * C_DIM + l0];
                        r3[i] = sb[tn * C_DIM + l1];
                        rb[i] = sb[tn * C_DIM + BLANK];
                    }

                    const float pa3 = wshr1_f(a3) * sSeed;  // alpha[4l-1]
                    const float n0 = Pb * (a0 + pa3);
                    const float n1 = P1 * (a1 + a0 + sk1 * pa3);
                    const float n2 = Pb * (a2 + a1);
                    const float n3 = P3 * (a3 + a2 + sk3 * a1);
                    const float n4 = Pb * (a4 + a3);
                    a0 = n0; a1 = n1; a2 = n2; a3 = n3; a4 = n4;

                    if ((i & 3) == 3) {
                        // per-lane rescale every 4 steps (decay >= ~2^-93)
                        const float m = fmaxf(fmaxf(fmaxf(a0, a1), fmaxf(a2, a3)), a4);
                        const bool has = m > 0.0f;
                        int eb = (int)((__float_as_uint(m) >> 23) & 0xFFu);
                        eb = eb < 1 ? 1 : eb;           // denormal m -> scale up
                        if (has) {
                            const float scl = __uint_as_float((unsigned)(254 - eb) << 23);
                            a0 *= scl; a1 *= scl; a2 *= scl; a3 *= scl; a4 *= scl;
                            E += eb - 127;
                        }
                        int pE = wshr1_i(E);
                        if (!has && lane > 0) E = pE;   // empty lane adopts E
                        pE = wshr1_i(E);
                        const int d = pE - E;
                        sSeed = (lane == 0 || d < -126)
                              ? 0.0f
                              : __uint_as_float((unsigned)(127 + (d > 126 ? 126 : d)) << 23);
                    }
                }
            }
            __builtin_amdgcn_sched_barrier(0);          // no LDS reads below barrier
            __builtin_amdgcn_s_barrier();
        }

        if (lane == 63)                                 // states 255 (a3) + 256 (a4)
            out[b] = -((log2f(a3 + a4) + (float)E) * LN2F);
    }
}

extern "C" void kernel_launch(void* const* d_in, const int* in_sizes, int n_in,
                              void* d_out, int out_size, void* d_ws, size_t ws_size,
                              hipStream_t stream)
{
    const int*   yt  = (const int*)d_in[0];
    const float* yh  = (const float*)d_in[1];
    float*       out = (float*)d_out;
    ctc_fused<<<dim3(B_DIM), dim3(128), 0, stream>>>(yt, yh, out);
}

// Round 17
// 40.817 us; speedup vs baseline: 3.3743x; 1.6591x over previous
//
#include <hip/hip_runtime.h>

// CTC batch cost (Keras: blank=C-1, full lengths).
// R17: forward/backward split. P(y) = sum_s alpha_511[s] * beta_511[s].
// 128 blocks: block 2b+0 = forward scan rows t=0..511 of batch b;
// block 2b+1 = backward scan t=1023..512. Each block: R16's proven
// producer/consumer pair (wave1 streams whole 2KB rows into LDS via
// global_load_lds dwordx4; wave0 consumes via LDS gather + DPP chain).
// 512 steps per block instead of 1024 -> ~2x via CU parallelism (the
// fused kernel was wave-latency-bound at ~68us regardless of producer).
// Terminal per-lane states (5 vals + exponent) -> d_ws; ctc_combine does
// the exponent-aligned dot + log per row.
// Backward recurrence (gamma = beta): bn[s] = P_t[s]*gamma_t[s];
//   gamma_{t-1}[s] = bn[s] + bn[s+1] + allowed(s+2)*bn[s+2].
// Lane l owns s=4l..4l+3 (+phantom 4l+4; real on lane 63 = state 256).
// Blank prob is state-uniform, so x0 (=neighbor bn0) == local bn4: only
// ONE cross-lane value per step (x1 via DPP wave_shl:1 = 0x130).
// Per-lane pow2 rescale every 4 steps, exponent adoption toward the
// propagation front (fwd: from lane l-1; bwd: from lane l+1).

constexpr int   B_DIM = 64;
constexpr int   T_LEN = 1024;
constexpr int   C_DIM = 512;
constexpr int   L_LEN = 128;
constexpr int   BLANK = C_DIM - 1;
constexpr int   HALF  = T_LEN / 2;     // 512 steps per direction
constexpr int   TC    = 16;            // timesteps per chunk
constexpr int   NCH   = HALF / TC;     // 32 chunks
constexpr float EPSF  = 1e-7f;
constexpr float LN2F  = 0.69314718055994530942f;

// DPP lane shifts (bound_ctrl=0-fill). 0x138: lane l <- l-1 (verified R2-R16).
__device__ __forceinline__ float wshr1_f(float x) {
    return __int_as_float(__builtin_amdgcn_update_dpp(
        0, __float_as_int(x), 0x138, 0xf, 0xf, true));
}
__device__ __forceinline__ int wshr1_i(int x) {
    return __builtin_amdgcn_update_dpp(0, x, 0x138, 0xf, 0xf, true);
}
// 0x130: lane l <- l+1 (wave_shl:1), lane 63 gets 0.
__device__ __forceinline__ float wshl1_f(float x) {
    return __int_as_float(__builtin_amdgcn_update_dpp(
        0, __float_as_int(x), 0x130, 0xf, 0xf, true));
}
__device__ __forceinline__ int wshl1_i(int x) {
    return __builtin_amdgcn_update_dpp(0, x, 0x130, 0xf, 0xf, true);
}

__global__ __launch_bounds__(128, 1)
void ctc_fb(const int* __restrict__ yt, const float* __restrict__ yh,
            float* __restrict__ st)
{
    __shared__ float sbuf[2][TC][C_DIM];      // 64 KB

    const int bid  = blockIdx.x;
    const int b    = bid >> 1;
    const int dir  = bid & 1;                 // 0 = forward, 1 = backward
    const int tid  = threadIdx.x;
    const int lane = tid & 63;
    const int wid  = tid >> 6;                // 0 consumer, 1 producer

    const int* __restrict__ lb = yt + b * L_LEN;
    const float* __restrict__ yhb = yh + (size_t)b * T_LEN * C_DIM;

    if (wid == 1) {
        // ---- producer: stream whole rows coalesced ------------------------
        auto stage = [&](int ch) {            // TC rows x 2 dwordx4 loads
            float* d = &sbuf[ch & 1][0][0];
            const int row0 = dir == 0 ? ch * TC : T_LEN - TC * (ch + 1);
            const float* g = yhb + (size_t)row0 * C_DIM + lane * 4;
#pragma unroll
            for (int i = 0; i < TC; ++i) {
#pragma unroll
                for (int h = 0; h < 2; ++h) {
                    __builtin_amdgcn_global_load_lds(
                        (const __attribute__((address_space(1))) void*)
                            (g + i * C_DIM + h * 256),
                        (__attribute__((address_space(3))) void*)
                            (d + i * C_DIM + h * 256),
                        16, 0, 0);
                }
            }
        };
        stage(0);
        asm volatile("s_waitcnt vmcnt(0)" ::: "memory");
        __builtin_amdgcn_sched_barrier(0);
        __builtin_amdgcn_s_barrier();
#pragma unroll 1
        for (int c = 0; c < NCH; ++c) {
            if (c + 1 < NCH) stage(c + 1);
            asm volatile("s_waitcnt vmcnt(0)" ::: "memory");
            __builtin_amdgcn_sched_barrier(0);
            __builtin_amdgcn_s_barrier();
        }
        return;
    }

    // -------- consumer -----------------------------------------------------
    const int l0 = lb[2 * lane];
    const int l1 = lb[2 * lane + 1];
    float* me = st + ((size_t)(dir * B_DIM + b) * 64 + lane) * 6;

    if (dir == 0) {
        // ================= forward: alpha_0 .. alpha_511 ===================
        const int lp = lane ? lb[2 * lane - 1] : 0;
        const float sk1 = (lane > 0 && l0 != lp && l0 != BLANK) ? 1.0f : 0.0f;
        const float sk3 = (l1 != l0 && l1 != BLANK) ? 1.0f : 0.0f;

        float a0 = (lane == 0) ? 1.0f : 0.0f;   // "t=-1" init trick
        float a1 = 0.0f, a2 = 0.0f, a3 = 0.0f, a4 = 0.0f;
        int   E  = 0;
        float sSeed = (lane == 0) ? 0.0f : 1.0f;

        __builtin_amdgcn_s_barrier();

        float r1[8], r3[8], rb[8];
#pragma unroll 1
        for (int c = 0; c < NCH; ++c) {
            __builtin_amdgcn_sched_barrier(0);
            const float* sb = &sbuf[c & 1][0][0];
#pragma unroll
            for (int i = 0; i < 8; ++i) {
                r1[i] = sb[i * C_DIM + l0];
                r3[i] = sb[i * C_DIM + l1];
                rb[i] = sb[i * C_DIM + BLANK];
            }
#pragma unroll
            for (int tq = 0; tq < 2; ++tq) {
#pragma unroll
                for (int i = 0; i < 8; ++i) {
                    const float P1 = r1[i] + EPSF;
                    const float P3 = r3[i] + EPSF;
                    const float Pb = rb[i] + EPSF;
                    if (tq == 0) {
                        r1[i] = sb[(i + 8) * C_DIM + l0];
                        r3[i] = sb[(i + 8) * C_DIM + l1];
                        rb[i] = sb[(i + 8) * C_DIM + BLANK];
                    }
                    const float pa3 = wshr1_f(a3) * sSeed;
                    const float n0 = Pb * (a0 + pa3);
                    const float n1 = P1 * (a1 + a0 + sk1 * pa3);
                    const float n2 = Pb * (a2 + a1);
                    const float n3 = P3 * (a3 + a2 + sk3 * a1);
                    const float n4 = Pb * (a4 + a3);
                    a0 = n0; a1 = n1; a2 = n2; a3 = n3; a4 = n4;

                    if ((i & 3) == 3) {
                        const float m = fmaxf(fmaxf(fmaxf(a0, a1), fmaxf(a2, a3)), a4);
                        const bool has = m > 0.0f;
                        int eb = (int)((__float_as_uint(m) >> 23) & 0xFFu);
                        eb = eb < 1 ? 1 : eb;
                        if (has) {
                            const float scl = __uint_as_float((unsigned)(254 - eb) << 23);
                            a0 *= scl; a1 *= scl; a2 *= scl; a3 *= scl; a4 *= scl;
                            E += eb - 127;
                        }
                        int pE = wshr1_i(E);
                        if (!has && lane > 0) E = pE;
                        pE = wshr1_i(E);
                        const int d = pE - E;
                        sSeed = (lane == 0 || d < -126)
                              ? 0.0f
                              : __uint_as_float((unsigned)(127 + (d > 126 ? 126 : d)) << 23);
                    }
                }
            }
            __builtin_amdgcn_sched_barrier(0);
            __builtin_amdgcn_s_barrier();
        }
        me[0] = a0; me[1] = a1; me[2] = a2; me[3] = a3; me[4] = a4;
        me[5] = __int_as_float(E);
    } else {
        // ================= backward: gamma_1023 -> gamma_511 ===============
        const float skb1 = (l1 != l0 && l1 != BLANK) ? 1.0f : 0.0f;   // s=4l+1 -> 4l+3
        const int ln = (lane < 63) ? lb[2 * lane + 2] : 0;            // label(4l+5)
        const float skb3 = (lane < 63 && ln != l1 && ln != BLANK) ? 1.0f : 0.0f;

        float c0 = 0.0f, c1 = 0.0f, c2 = 0.0f;
        float c3 = (lane == 63) ? 1.0f : 0.0f;   // gamma_1023[255]=1
        float c4 = (lane == 63) ? 1.0f : 0.0f;   // gamma_1023[256]=1
        int   E  = 0;
        float sSeed = (lane == 63) ? 0.0f : 1.0f;  // 2^(E_{l+1}-E_l), 0 at lane 63

        __builtin_amdgcn_s_barrier();

        float r1[8], r3[8], rb[8];
#pragma unroll 1
        for (int c = 0; c < NCH; ++c) {
            __builtin_amdgcn_sched_barrier(0);
            const float* sb = &sbuf[c & 1][0][0];
            // step j uses LDS row (TC-1-j): t descending
#pragma unroll
            for (int i = 0; i < 8; ++i) {
                const int rr = TC - 1 - i;
                r1[i] = sb[rr * C_DIM + l0];
                r3[i] = sb[rr * C_DIM + l1];
                rb[i] = sb[rr * C_DIM + BLANK];
            }
#pragma unroll
            for (int tq = 0; tq < 2; ++tq) {
#pragma unroll
                for (int i = 0; i < 8; ++i) {
                    const float P1 = r1[i] + EPSF;
                    const float P3 = r3[i] + EPSF;
                    const float Pb = rb[i] + EPSF;
                    if (tq == 0) {
                        const int rr = 7 - i;             // rows for j=8..15
                        r1[i] = sb[rr * C_DIM + l0];
                        r3[i] = sb[rr * C_DIM + l1];
                        rb[i] = sb[rr * C_DIM + BLANK];
                    }
                    const float bn0 = c0 * Pb;
                    const float bn1 = c1 * P1;
                    const float bn2 = c2 * Pb;
                    const float bn3 = c3 * P3;
                    const float bn4 = c4 * Pb;            // == neighbor's bn0
                    const float x1  = wshl1_f(bn1) * sSeed;
                    c0 = bn0 + bn1;
                    c1 = bn1 + bn2 + skb1 * bn3;
                    c2 = bn2 + bn3;
                    c3 = bn3 + bn4 + skb3 * x1;
                    c4 = bn4 + x1;

                    if ((i & 3) == 3) {
                        const float m = fmaxf(fmaxf(fmaxf(c0, c1), fmaxf(c2, c3)), c4);
                        const bool has = m > 0.0f;
                        int eb = (int)((__float_as_uint(m) >> 23) & 0xFFu);
                        eb = eb < 1 ? 1 : eb;
                        if (has) {
                            const float scl = __uint_as_float((unsigned)(254 - eb) << 23);
                            c0 *= scl; c1 *= scl; c2 *= scl; c3 *= scl; c4 *= scl;
                            E += eb - 127;
                        }
                        int pE = wshl1_i(E);
                        if (!has && lane < 63) E = pE;
                        pE = wshl1_i(E);
                        const int d = pE - E;
                        sSeed = (lane == 63 || d < -126)
                              ? 0.0f
                              : __uint_as_float((unsigned)(127 + (d > 126 ? 126 : d)) << 23);
                    }
                }
            }
            __builtin_amdgcn_sched_barrier(0);
            __builtin_amdgcn_s_barrier();
        }
        me[0] = c0; me[1] = c1; me[2] = c2; me[3] = c3; me[4] = c4;
        me[5] = __int_as_float(E);
    }
}

__global__ __launch_bounds__(64)
void ctc_combine(const float* __restrict__ st, float* __restrict__ out)
{
    const int b    = blockIdx.x;
    const int lane = threadIdx.x;
    const float* f = st + ((size_t)b * 64 + lane) * 6;
    const float* g = st + ((size_t)(B_DIM + b) * 64 + lane) * 6;

    float v = f[0] * g[0] + f[1] * g[1] + f[2] * g[2] + f[3] * g[3];
    if (lane == 63) v += f[4] * g[4];        // state 256
    const int e = __float_as_int(f[5]) + __float_as_int(g[5]);
    float L = (v > 0.0f) ? (log2f(v) + (float)e) : -1e30f;

    float M = L;
#pragma unroll
    for (int d = 1; d < 64; d <<= 1) M = fmaxf(M, __shfl_xor(M, d));
    float s = (L > -1e29f) ? exp2f(L - M) : 0.0f;
#pragma unroll
    for (int d = 1; d < 64; d <<= 1) s += __shfl_xor(s, d);

    if (lane == 0) out[b] = -((M + log2f(s)) * LN2F);
}

extern "C" void kernel_launch(void* const* d_in, const int* in_sizes, int n_in,
                              void* d_out, int out_size, void* d_ws, size_t ws_size,
                              hipStream_t stream)
{
    const int*   yt  = (const int*)d_in[0];
    const float* yh  = (const float*)d_in[1];
    float*       out = (float*)d_out;
    float*       st  = (float*)d_ws;       // 2*64*64*6 floats = 192 KB << ws
    ctc_fb<<<dim3(2 * B_DIM), dim3(128), 0, stream>>>(yt, yh, st);
    ctc_combine<<<dim3(B_DIM), dim3(64), 0, stream>>>(st, out);
}